// Round 1
// baseline (6107.039 us; speedup 1.0000x reference)
//
#include <hip/hip_runtime.h>
#include <hip/hip_bf16.h>

// Smoothed Viterbi: V_{t+1}[b,i] = logsumexp_j(theta[t,b,i,j] + V_t[b,j]); out[b]=lse_i V_T[b,i]
// T=128, B=8, S=512. theta fp32, 1 GiB total — memory-bound streaming with a
// sequential T dependency. Single cooperative kernel; per-batch device-scope
// barriers (64 blocks/batch); theta[t+1] prefetched to registers before the
// barrier spin so HBM stays busy during synchronization.

constexpr int TT = 128;
constexpr int SS = 512;
constexpr int BB = 8;
constexpr int BLOCKS_PER_BATCH = 64;   // 8 rows per block
constexpr int NBLOCKS = BB * BLOCKS_PER_BATCH;   // 512
constexpr int NTHREADS = 256;          // 4 waves; wave handles 2 rows

struct Row8 { float v[8]; };

__device__ inline Row8 load_row8(const float* __restrict__ p) {
    Row8 r;
    float4 a = *(const float4*)p;
    float4 b = *(const float4*)(p + 4);
    r.v[0] = a.x; r.v[1] = a.y; r.v[2] = a.z; r.v[3] = a.w;
    r.v[4] = b.x; r.v[5] = b.y; r.v[6] = b.z; r.v[7] = b.w;
    return r;
}

__global__ __launch_bounds__(NTHREADS, 2)
void viterbi_kernel(const float* __restrict__ theta,
                    float* __restrict__ out,
                    float* __restrict__ vbuf,        // [2][BB*SS] double buffer
                    unsigned int* __restrict__ cnt)  // [BB] counters, 256B apart
{
    const int bid = blockIdx.x;
    const int b   = bid >> 6;          // batch
    const int k   = bid & 63;          // block-within-batch
    const int tid = threadIdx.x;
    const int wv  = tid >> 6;          // wave 0..3
    const int ln  = tid & 63;          // lane
    const int r0  = (k << 3) + (wv << 1);   // this wave's rows: r0, r0+1
    const int j0  = ln << 3;                // this lane's 8 columns

    const size_t stepStride = (size_t)BB * SS * SS;   // floats per timestep
    const float* tp = theta + ((size_t)b * SS + (size_t)r0) * SS + j0;

    unsigned int* mycnt = cnt + b * 64;   // 256-byte padding between batches

    // Prime: load theta[0] rows into registers.
    Row8 cur0 = load_row8(tp);
    Row8 cur1 = load_row8(tp + SS);

    for (int t = 0; t < TT; ++t) {
        // ---- prefetch theta[t+1] (clamped at last step; harmless re-read) ----
        const int tn = (t + 1 < TT) ? (t + 1) : t;
        const float* np = tp + (size_t)tn * stepStride;
        Row8 nxt0 = load_row8(np);
        Row8 nxt1 = load_row8(np + SS);

        // ---- wait for V_t, then load it ----
        float vp[8];
        float shift;
        if (t == 0) {
            #pragma unroll
            for (int i = 0; i < 8; ++i) vp[i] = 0.0f;
            shift = 0.0f;
        } else {
            const unsigned int tgt = 64u * (unsigned int)t;
            if (tid == 0) {
                while (__hip_atomic_load(mycnt, __ATOMIC_ACQUIRE,
                                         __HIP_MEMORY_SCOPE_AGENT) < tgt) {
                    __builtin_amdgcn_s_sleep(2);
                }
            }
            __syncthreads();
            const float* vr = vbuf + (size_t)(t & 1) * (BB * SS) + b * SS + j0;
            #pragma unroll
            for (int i = 0; i < 8; ++i)
                vp[i] = __hip_atomic_load(vr + i, __ATOMIC_RELAXED,
                                          __HIP_MEMORY_SCOPE_AGENT);
            shift = __shfl(vp[0], 0);   // V[b,0] — safe shift (values clustered)
        }

        // ---- compute partial sums for 2 rows ----
        float s0 = 0.0f, s1 = 0.0f;
        #pragma unroll
        for (int i = 0; i < 8; ++i) s0 += __expf(cur0.v[i] + vp[i] - shift);
        #pragma unroll
        for (int i = 0; i < 8; ++i) s1 += __expf(cur1.v[i] + vp[i] - shift);

        // ---- wave64 butterfly reduce ----
        #pragma unroll
        for (int m = 1; m < 64; m <<= 1) {
            s0 += __shfl_xor(s0, m);
            s1 += __shfl_xor(s1, m);
        }

        // ---- lane 0 writes V_{t+1}[b, r0], [b, r0+1] (cache-bypassing) ----
        if (ln == 0) {
            float* vw = vbuf + (size_t)((t + 1) & 1) * (BB * SS) + b * SS + r0;
            __hip_atomic_store(vw,     shift + __logf(s0), __ATOMIC_RELAXED,
                               __HIP_MEMORY_SCOPE_AGENT);
            __hip_atomic_store(vw + 1, shift + __logf(s1), __ATOMIC_RELAXED,
                               __HIP_MEMORY_SCOPE_AGENT);
        }

        __syncthreads();   // drains vmcnt: all 8 row-stores done before signal
        if (tid == 0) {
            __hip_atomic_fetch_add(mycnt, 1u, __ATOMIC_RELEASE,
                                   __HIP_MEMORY_SCOPE_AGENT);
        }

        cur0 = nxt0; cur1 = nxt1;
    }

    // ---- final reduction: out[b] = lse_i V_T[b,i], one wave per batch ----
    if (k == 0) {
        const unsigned int tgt = 64u * (unsigned int)TT;
        if (tid == 0) {
            while (__hip_atomic_load(mycnt, __ATOMIC_ACQUIRE,
                                     __HIP_MEMORY_SCOPE_AGENT) < tgt) {
                __builtin_amdgcn_s_sleep(2);
            }
        }
        __syncthreads();
        if (wv == 0) {
            const float* vr = vbuf + (size_t)(TT & 1) * (BB * SS) + b * SS + j0;
            float vp[8];
            #pragma unroll
            for (int i = 0; i < 8; ++i)
                vp[i] = __hip_atomic_load(vr + i, __ATOMIC_RELAXED,
                                          __HIP_MEMORY_SCOPE_AGENT);
            float shift = __shfl(vp[0], 0);
            float s = 0.0f;
            #pragma unroll
            for (int i = 0; i < 8; ++i) s += __expf(vp[i] - shift);
            #pragma unroll
            for (int m = 1; m < 64; m <<= 1) s += __shfl_xor(s, m);
            if (ln == 0) out[b] = shift + __logf(s);
        }
    }
}

extern "C" void kernel_launch(void* const* d_in, const int* in_sizes, int n_in,
                              void* d_out, int out_size, void* d_ws, size_t ws_size,
                              hipStream_t stream) {
    (void)in_sizes; (void)n_in; (void)out_size; (void)ws_size;
    const float* theta = (const float*)d_in[0];
    float* out = (float*)d_out;

    // d_ws layout: [0, 32768) two V buffers (2*8*512 fp32); [32768, +2048) counters
    float* vbuf = (float*)d_ws;
    unsigned int* cnt = (unsigned int*)((char*)d_ws + 2 * BB * SS * sizeof(float));

    // Counters must start at 0 (d_ws is poisoned 0xAA before every launch).
    hipMemsetAsync(cnt, 0, BB * 64 * sizeof(unsigned int), stream);

    void* args[] = { (void*)&theta, (void*)&out, (void*)&vbuf, (void*)&cnt };
    hipLaunchCooperativeKernel((void*)viterbi_kernel,
                               dim3(NBLOCKS), dim3(NTHREADS),
                               args, 0, stream);
}